// Round 2
// baseline (111.458 us; speedup 1.0000x reference)
//
#include <hip/hip_runtime.h>

#define K_BINS 1025
#define T_LEN  2000
#define NF     128

__device__ __forceinline__ float softplusf(float x) {
    // matches jax.nn.softplus = max(x,0) + log1p(exp(-|x|))
    return fmaxf(x, 0.0f) + log1pf(expf(-fabsf(x)));
}

// out[b2, t, 4*bp + w] = sum_k fb[b2 + 32w, k] * spec[bp, k, t]
//   (from reshape(F,B,T)+transpose: f2 = 4*b' + (f'>>5), b2 = f'&31)
// Thread owns (b2, bp, t..t+3): 4 filters x 4 t accumulators, float4 loads along t.
// Lane map: t4 = lane&3 (4 consecutive float4s), bp = lane>>2 (16 values)
//   => per wave-load: 16 segments of 64 B, fully used. 1 KiB / instruction.
__global__ __launch_bounds__(256) void fb_apply_kernel(
        const float* __restrict__ spec,
        const float* __restrict__ cf,
        const float* __restrict__ bwv,
        const float* __restrict__ fs,
        float*       __restrict__ out) {
    const int lane = threadIdx.x & 63;
    const int wid  = threadIdx.x >> 6;
    const int b2   = blockIdx.y * 4 + wid;              // 0..31 (filter low 5 bits)
    const int bp   = blockIdx.z * 16 + (lane >> 2);     // batch b', 0..31
    const int tb   = blockIdx.x * 16 + 4 * (lane & 3);  // t base, 125*16 == 2000

    const float* specb = spec + (size_t)bp * (K_BINS * T_LEN) + tb;

    float4 acc[4];
#pragma unroll
    for (int w = 0; w < 4; ++w) {
        const int f = b2 + 32 * w;
        // wave-uniform filter params (b2 is per-wave constant; L1-broadcast loads)
        float c  = cf[f];
        float bw = softplusf(bwv[f]) + 0.001f;
        float s0 = softplusf(fs[2 * f])     + 0.1f;
        float s1 = softplusf(fs[2 * f + 1]) + 0.1f;
        float left  = c - bw * s0;
        float right = c + bw * s1;
        float invcl = 1.0f / (c - left + 1e-8f);
        float invrc = 1.0f / (right - c + 1e-8f);
        int klo = max(0, (int)ceilf(left));
        int khi = min(K_BINS - 1, (int)floorf(right));

        float4 a = make_float4(0.f, 0.f, 0.f, 0.f);
        const float* sp = specb + (size_t)klo * T_LEN;
        for (int k = klo; k <= khi; ++k) {
            float fk  = (float)k;
            float wgt = (fk <= c) ? (fk - left) * invcl
                                  : fmaf(-(fk - c), invrc, 1.0f);
            float4 v = *reinterpret_cast<const float4*>(sp);
            a.x = fmaf(wgt, v.x, a.x);
            a.y = fmaf(wgt, v.y, a.y);
            a.z = fmaf(wgt, v.z, a.z);
            a.w = fmaf(wgt, v.w, a.w);
            sp += T_LEN;
        }
        acc[w] = a;
    }

    // out element (b2, tb+j, 4*bp + w) = acc[w] component j
    float* ob = out + (size_t)b2 * (T_LEN * NF) + (size_t)tb * NF + 4 * bp;
    *reinterpret_cast<float4*>(ob)       = make_float4(acc[0].x, acc[1].x, acc[2].x, acc[3].x);
    *reinterpret_cast<float4*>(ob + 128) = make_float4(acc[0].y, acc[1].y, acc[2].y, acc[3].y);
    *reinterpret_cast<float4*>(ob + 256) = make_float4(acc[0].z, acc[1].z, acc[2].z, acc[3].z);
    *reinterpret_cast<float4*>(ob + 384) = make_float4(acc[0].w, acc[1].w, acc[2].w, acc[3].w);
}

extern "C" void kernel_launch(void* const* d_in, const int* in_sizes, int n_in,
                              void* d_out, int out_size, void* d_ws, size_t ws_size,
                              hipStream_t stream) {
    const float* spec = (const float*)d_in[0];   // (32, 1025, 2000) f32
    const float* cf   = (const float*)d_in[1];   // (128,)
    const float* bwv  = (const float*)d_in[2];   // (128,)
    const float* fs   = (const float*)d_in[3];   // (128, 2)
    float* out = (float*)d_out;                  // (32, 2000, 128) f32

    fb_apply_kernel<<<dim3(125, 8, 2), 256, 0, stream>>>(spec, cf, bwv, fs, out);
}

// Round 3
// 82.610 us; speedup vs baseline: 1.3492x; 1.3492x over previous
//
#include <hip/hip_runtime.h>

#define K_BINS 1025
#define T_LEN  2000
#define NF     128
#define NB     32
#define TT     80        // phase-2 t-tile; 2000 = 25*80

__device__ __forceinline__ float softplusf(float x) {
    // matches jax.nn.softplus = max(x,0) + log1p(exp(-|x|))
    return fmaxf(x, 0.0f) + log1pf(expf(-fabsf(x)));
}

// Phase 1: F[f][bp][t] = sum_k w_f(k) * spec[bp][k][t]
// Wave = (filter f, batch bp), owns the full t-row (2000 floats = 500 float4).
// Each k-step reads one contiguous 8 KB row as 8 x 1 KiB wave-loads -> pure
// sequential HBM streams. Block = (f-quad, bp): the 4 waves' k-ranges overlap
// -> L2 absorbs within-block re-reads; adjacent quads overlap via L3.
__global__ __launch_bounds__(256) void fb_phase1(
        const float* __restrict__ spec,
        const float* __restrict__ cf,
        const float* __restrict__ bwv,
        const float* __restrict__ fs,
        float*       __restrict__ F) {
    const int lane = threadIdx.x & 63;
    const int w    = threadIdx.x >> 6;
    const int f    = 4 * blockIdx.x + w;   // 0..127
    const int bp   = blockIdx.y;           // 0..31

    // wave-uniform filter params
    float c  = cf[f];
    float bw = softplusf(bwv[f]) + 0.001f;
    float s0 = softplusf(fs[2 * f])     + 0.1f;
    float s1 = softplusf(fs[2 * f + 1]) + 0.1f;
    float left  = c - bw * s0;
    float right = c + bw * s1;
    float invcl = 1.0f / (c - left + 1e-8f);
    float invrc = 1.0f / (right - c + 1e-8f);
    int klo = max(0, (int)ceilf(left));
    int khi = min(K_BINS - 1, (int)floorf(right));

    float4 acc[8];
#pragma unroll
    for (int j = 0; j < 8; ++j) acc[j] = make_float4(0.f, 0.f, 0.f, 0.f);

    const float4* srow = (const float4*)(spec + ((size_t)bp * K_BINS + klo) * T_LEN);
    for (int k = klo; k <= khi; ++k) {
        float fk  = (float)k;
        float wgt = (fk <= c) ? (fk - left) * invcl
                              : fmaf(-(fk - c), invrc, 1.0f);
#pragma unroll
        for (int j = 0; j < 8; ++j) {
            int idx = j * 64 + lane;           // 0..511; 500 float4 per row
            if (idx < 500) {                   // guard only live for j==7
                float4 v = srow[idx];
                acc[j].x = fmaf(wgt, v.x, acc[j].x);
                acc[j].y = fmaf(wgt, v.y, acc[j].y);
                acc[j].z = fmaf(wgt, v.z, acc[j].z);
                acc[j].w = fmaf(wgt, v.w, acc[j].w);
            }
        }
        srow += 500;                           // next k-row (8000 B)
    }

    float4* frow = (float4*)(F + ((size_t)f * NB + bp) * T_LEN);
#pragma unroll
    for (int j = 0; j < 8; ++j) {
        int idx = j * 64 + lane;
        if (idx < 500) frow[idx] = acc[j];
    }
}

// Phase 2: out[b2][t][4*bp + w] = F[b2 + 32*w][bp][t]
// LDS tile 128 x 80 (stride 81 -> conflict-free column reads).
// Writes: float2 per lane -> 512 B contiguous per wave-store.
__global__ __launch_bounds__(256) void fb_phase2(
        const float* __restrict__ F,
        float*       __restrict__ out) {
    __shared__ float tile[NF][TT + 1];
    const int b2 = blockIdx.y;          // 0..31
    const int t0 = blockIdx.x * TT;     // 25 tiles

    // load: row = f2 = 4*bp + w  (128 rows x 20 float4)
    for (int idx = threadIdx.x; idx < NF * (TT / 4); idx += 256) {
        int row = idx / (TT / 4);
        int l   = idx % (TT / 4);
        int bp  = row >> 2;
        int w   = row & 3;
        int fsrc = b2 + 32 * w;
        const float4* src = (const float4*)(F + ((size_t)fsrc * NB + bp) * T_LEN + t0);
        float4 v = src[l];
        tile[row][4 * l + 0] = v.x;
        tile[row][4 * l + 1] = v.y;
        tile[row][4 * l + 2] = v.z;
        tile[row][4 * l + 3] = v.w;
    }
    __syncthreads();

    // store: out[b2][t0+r][c], c = 0..127 contiguous
    const int c2 = (threadIdx.x & 63) * 2;   // f2 pair
    const int r0 = threadIdx.x >> 6;         // 0..3
    float* obase = out + ((size_t)b2 * T_LEN + t0) * NF;
    for (int r = r0; r < TT; r += 4) {
        float2 v = make_float2(tile[c2][r], tile[c2 + 1][r]);
        *reinterpret_cast<float2*>(obase + (size_t)r * NF + c2) = v;
    }
}

extern "C" void kernel_launch(void* const* d_in, const int* in_sizes, int n_in,
                              void* d_out, int out_size, void* d_ws, size_t ws_size,
                              hipStream_t stream) {
    const float* spec = (const float*)d_in[0];   // (32, 1025, 2000) f32
    const float* cf   = (const float*)d_in[1];   // (128,)
    const float* bwv  = (const float*)d_in[2];   // (128,)
    const float* fs   = (const float*)d_in[3];   // (128, 2)
    float* out = (float*)d_out;                  // (32, 2000, 128) f32
    float* F   = (float*)d_ws;                   // (128, 32, 2000) f32 = 32.8 MB

    fb_phase1<<<dim3(32, 32), 256, 0, stream>>>(spec, cf, bwv, fs, F);
    fb_phase2<<<dim3(25, 32), 256, 0, stream>>>(F, out);
}

// Round 4
// 70.562 us; speedup vs baseline: 1.5796x; 1.1707x over previous
//
#include <hip/hip_runtime.h>

#define K_BINS 1025
#define T_LEN  2000
#define NF     128
#define NB     32

__device__ __forceinline__ float softplusf(float x) {
    // matches jax.nn.softplus = max(x,0) + log1p(exp(-|x|))
    return fmaxf(x, 0.0f) + log1pf(expf(-fabsf(x)));
}

// Fused: out[b2][t][4*bp + w] = sum_k w_f(k) * spec[bp][k][t],  f = b2 + 32*w
// Block = (bp-quad q, b2), 512 threads = 8 waves.
// Wave (w = wid>>1, h = wid&1): filter b2+32w over bp = 4q+2h+{0,1}.
// Reads: contiguous 8 KB k-rows (float4, idx = 64j+lane). ~12 rows/filter.
// Epilogue: 8 chunks of 256 t via LDS [256][17] -> out stores are full 64 B
// lines, 1 KiB contiguous per wave-store (block owns f2 in [16q, 16q+16)).
__global__ __launch_bounds__(512) void fb_fused(
        const float* __restrict__ spec,
        const float* __restrict__ cf,
        const float* __restrict__ bwv,
        const float* __restrict__ fs,
        float*       __restrict__ out) {
    const int q    = blockIdx.x;          // bp-quad 0..7 (→ XCD q)
    const int b2   = blockIdx.y;          // 0..31
    const int tid  = threadIdx.x;
    const int lane = tid & 63;
    const int wid  = tid >> 6;            // 0..7
    const int w    = wid >> 1;            // filter part 0..3
    const int h    = wid & 1;             // bp half
    const int f    = b2 + 32 * w;
    const int bp0  = 4 * q + 2 * h;

    // wave-uniform filter params
    float c  = cf[f];
    float bw = softplusf(bwv[f]) + 0.001f;
    float s0 = softplusf(fs[2 * f])     + 0.1f;
    float s1 = softplusf(fs[2 * f + 1]) + 0.1f;
    float left  = c - bw * s0;
    float right = c + bw * s1;
    float invcl = 1.0f / (c - left + 1e-8f);
    float invrc = 1.0f / (right - c + 1e-8f);
    int klo = max(0, (int)ceilf(left));
    int khi = min(K_BINS - 1, (int)floorf(right));

    float4 acc[2][8];
#pragma unroll
    for (int s = 0; s < 2; ++s)
#pragma unroll
        for (int j = 0; j < 8; ++j) acc[s][j] = make_float4(0.f, 0.f, 0.f, 0.f);

    const float4* r0 = (const float4*)spec + ((size_t)bp0 * K_BINS + klo) * 500;
    const float4* r1 = r0 + (size_t)K_BINS * 500;
    for (int k = klo; k <= khi; ++k) {
        float fk  = (float)k;
        float wgt = (fk <= c) ? (fk - left) * invcl
                              : fmaf(-(fk - c), invrc, 1.0f);
#pragma unroll
        for (int j = 0; j < 8; ++j) {
            int idx = j * 64 + lane;          // 500 float4 per row
            if (idx < 500) {                  // only j==7 partially masked
                float4 v = r0[idx];
                acc[0][j].x = fmaf(wgt, v.x, acc[0][j].x);
                acc[0][j].y = fmaf(wgt, v.y, acc[0][j].y);
                acc[0][j].z = fmaf(wgt, v.z, acc[0][j].z);
                acc[0][j].w = fmaf(wgt, v.w, acc[0][j].w);
                float4 u = r1[idx];
                acc[1][j].x = fmaf(wgt, u.x, acc[1][j].x);
                acc[1][j].y = fmaf(wgt, u.y, acc[1][j].y);
                acc[1][j].z = fmaf(wgt, u.z, acc[1][j].z);
                acc[1][j].w = fmaf(wgt, u.w, acc[1][j].w);
            }
        }
        r0 += 500;
        r1 += 500;
    }

    // transpose + store, 8 chunks of 256 t
    __shared__ float tile[256][17];           // 16 f2 cols + 1 pad
    for (int j = 0; j < 8; ++j) {
        __syncthreads();                      // protect tile reuse
        int idx = j * 64 + lane;
        if (idx < 500) {
            int rb = 4 * lane;                // local t row base
#pragma unroll
            for (int s = 0; s < 2; ++s) {
                int cc = 4 * (2 * h + s) + w; // f2 - 16q
                tile[rb + 0][cc] = (&acc[s][j].x)[0];
                tile[rb + 1][cc] = (&acc[s][j].x)[1];
                tile[rb + 2][cc] = (&acc[s][j].x)[2];
                tile[rb + 3][cc] = (&acc[s][j].x)[3];
            }
        }
        __syncthreads();
#pragma unroll
        for (int it = 0; it < 2; ++it) {
            int r = 128 * it + (tid >> 2);    // 0..255
            int t = 256 * j + r;
            if (t < T_LEN) {
                int c4 = tid & 3;
                float4 v = make_float4(tile[r][4 * c4 + 0], tile[r][4 * c4 + 1],
                                       tile[r][4 * c4 + 2], tile[r][4 * c4 + 3]);
                *reinterpret_cast<float4*>(
                    out + ((size_t)b2 * T_LEN + t) * NF + 16 * q + 4 * c4) = v;
            }
        }
    }
}

extern "C" void kernel_launch(void* const* d_in, const int* in_sizes, int n_in,
                              void* d_out, int out_size, void* d_ws, size_t ws_size,
                              hipStream_t stream) {
    const float* spec = (const float*)d_in[0];   // (32, 1025, 2000) f32
    const float* cf   = (const float*)d_in[1];   // (128,)
    const float* bwv  = (const float*)d_in[2];   // (128,)
    const float* fs   = (const float*)d_in[3];   // (128, 2)
    float* out = (float*)d_out;                  // (32, 2000, 128) f32

    fb_fused<<<dim3(8, 32), 512, 0, stream>>>(spec, cf, bwv, fs, out);
}